// Round 10
// baseline (344.306 us; speedup 1.0000x reference)
//
#include <hip/hip_runtime.h>
#include <stdint.h>

// Problem: B=4, T=2048, D_IN=512, D_OUT=512, N_FILT=24.
// out[b,t,o] = sum_n phi[t,n] * cumsum_t( phi[t,n] * (M[n] @ x[b,t,:]) )[o]
// r20: Z (201MB materialized+reread) ELIMINATED. out = A + B:
//   B[t,o] = sum_n phi[t,n] * within-chunk-cumsum(z)[t,n,o]  (in GEMM epilogue)
//   A[t,o] = sum_n phi[t,n] * Gpref[chunk(t)][n,o]           (k_apply, post-prefix)
#define BQ 4
#define TT 2048
#define DF 512
#define DOUT 512
#define NF 24
#define CHF 8   // chunk rows

typedef __attribute__((ext_vector_type(8))) short short8;
typedef __attribute__((ext_vector_type(4))) float f32x4;

typedef __attribute__((address_space(3))) uint8_t       lds_u8;
typedef __attribute__((address_space(1))) const uint8_t glb_u8;

__device__ __forceinline__ float bf2f(unsigned short u) {
    union { unsigned int i; float f; } v; v.i = ((unsigned int)u) << 16; return v.f;
}
__device__ __forceinline__ unsigned short f2bf(float f) {
    union { float f; unsigned int i; } v; v.f = f;
    unsigned int r = v.i + 0x7FFFu + ((v.i >> 16) & 1u);  // RNE
    return (unsigned short)(r >> 16);
}
__device__ __forceinline__ float lo16f(unsigned int u) { return __uint_as_float(u << 16); }
__device__ __forceinline__ float hi16f(unsigned int u) { return __uint_as_float(u & 0xffff0000u); }

// ---------------------------------------------------------------------------
// Dtype sniffer (flag=1 => fp32 inputs).
// ---------------------------------------------------------------------------
__device__ __forceinline__ int plaus16(unsigned int h) {
    unsigned int e = (h >> 7) & 0xffu;
    return (e >= 97u && e <= 141u) || ((h & 0x7fffu) == 0u);
}

__global__ void k_detect(const unsigned int* __restrict__ X, int* __restrict__ flag)
{
    const int lane = threadIdx.x;  // 64 threads, 1 block
    int cnt = 0;
#pragma unroll
    for (int i = 0; i < 4; ++i) {
        unsigned int w = X[lane * 4 + i];
        cnt += (plaus16(w >> 16) && plaus16(w & 0xffffu)) ? 1 : 0;
    }
    for (int off = 32; off > 0; off >>= 1) cnt += __shfl_down(cnt, off);
    if (lane == 0) *flag = (cnt < 180) ? 1 : 0;
}

__global__ __launch_bounds__(256) void k_convf(
    const void* __restrict__ src, float* __restrict__ dst,
    const int* __restrict__ flag, int n)
{
    const int isf32 = *flag;
    int i = blockIdx.x * 256 + threadIdx.x;
    const int stride = gridDim.x * 256;
    for (; i < n; i += stride)
        dst[i] = isf32 ? ((const float*)src)[i]
                       : bf2f(((const unsigned short*)src)[i]);
}

// ---------------------------------------------------------------------------
// r16 prep: detect + convert X/M -> bf16, filters -> fp32, one kernel.
// ---------------------------------------------------------------------------
__global__ __launch_bounds__(256) void k_prep(
    const void* __restrict__ X, const void* __restrict__ Mw,
    const void* __restrict__ Fil,
    unsigned short* __restrict__ Xbf, unsigned short* __restrict__ Mbf,
    float* __restrict__ Fw, int n4x, int n4m, int n4f)
{
    __shared__ int sflag;
    const int tid = threadIdx.x;
    if (tid < 64) {
        int cnt = 0;
        const unsigned int* Xu = (const unsigned int*)X;
#pragma unroll
        for (int i = 0; i < 4; ++i) {
            unsigned int wd = Xu[tid * 4 + i];
            cnt += (plaus16(wd >> 16) && plaus16(wd & 0xffffu)) ? 1 : 0;
        }
        for (int off = 32; off > 0; off >>= 1) cnt += __shfl_down(cnt, off);
        if (tid == 0) sflag = (cnt < 180) ? 1 : 0;
    }
    __syncthreads();
    const int isf32 = sflag;

    const int total = n4x + n4m + n4f;
    for (int i = blockIdx.x * 256 + tid; i < total; i += gridDim.x * 256) {
        if (i < n4x) {
            ushort4 o;
            if (isf32) {
                float4 v = ((const float4*)X)[i];
                o.x = f2bf(v.x); o.y = f2bf(v.y); o.z = f2bf(v.z); o.w = f2bf(v.w);
            } else {
                o = ((const ushort4*)X)[i];
            }
            ((ushort4*)Xbf)[i] = o;
        } else if (i < n4x + n4m) {
            const int j = i - n4x;
            ushort4 o;
            if (isf32) {
                float4 v = ((const float4*)Mw)[j];
                o.x = f2bf(v.x); o.y = f2bf(v.y); o.z = f2bf(v.z); o.w = f2bf(v.w);
            } else {
                o = ((const ushort4*)Mw)[j];
            }
            ((ushort4*)Mbf)[j] = o;
        } else {
            const int j = i - n4x - n4m;
            if (isf32) {
                ((float4*)Fw)[j] = ((const float4*)Fil)[j];
            } else {
                ushort4 u = ((const ushort4*)Fil)[j];
                ((float4*)Fw)[j] = make_float4(bf2f(u.x), bf2f(u.y),
                                               bf2f(u.z), bf2f(u.w));
            }
        }
    }
}

// ---------------------------------------------------------------------------
// r20 FUSED GEMM (no Z): 64x128 tile, n-loop INSIDE (flattened 24n x 16kt,
// r12-proven 2-phase dbuf). Per-n epilogue, all in registers:
//   z[r] = acc*phi; in-lane 4-prefix; shfl_xor(p3,16) -> 8-row chunk cumsum
//   (C layout row=(lane>>4)*4+r => q-pairs {0,1},{2,3} are the 8-chunks);
//   Bacc += phi*cum; lanes q odd emit chunk totals -> Cs.
// After loop: Bacc -> Out (B-term). k_apply later adds the A-term.
// Regs ~115 (acc 32 + Bacc 32), LDS 30KB. grid (rows/64, 4), block 256.
// ---------------------------------------------------------------------------
__global__ __launch_bounds__(256, 3) void k_gemm_ns(
    const unsigned short* __restrict__ X,   // bf16 [B*T, DF]
    const unsigned short* __restrict__ Mw,  // bf16 [NF][DOUT][DF]
    const float* __restrict__ Fw,           // fp32 [TT][NF]
    float* __restrict__ Cs,                 // fp32 [chunkLocal][NF][512]
    float* __restrict__ Out,                // fp32 [B*T][512]
    int r0)
{
    // dbuf: each buf = A[64*32] (2048 sh) + B[128*32] (4096 sh) = 12KB
    __shared__ unsigned short sAB[2 * 6144];
    __shared__ float sPhi2[NF * 64];        // phi[n][row], 6KB

    const int tid  = threadIdx.x;
    const int lane = tid & 63;
    const int w    = tid >> 6;
    const int wm   = w & 1, wn = w >> 1;
    const int tm   = blockIdx.x;
    const int on0  = blockIdx.y * 128;
    const int rowL = tm * 64;          // local rows (Cs chunk indexing)
    const int rowG = r0 + rowL;        // global rows (X, phi, Out)

    for (int idx = tid; idx < NF * 64; idx += 256) {
        int n = idx >> 6, rr2 = idx & 63;
        sPhi2[idx] = Fw[((rowG + rr2) & (TT - 1)) * NF + n];
    }

    const unsigned short* Ag = X + (size_t)rowG * DF;

    auto stage = [&](int m) {
        const int n = m >> 4, kt = m & 15;
        lds_u8* base = (lds_u8*)sAB + (m & 1) * 12288;
        // A: 256 16B-chunks (64 rows x 4), one per thread
        {
            const int c = w * 64 + lane;
            const int r = c >> 2, qs = c & 3;
            const int qg = qs ^ ((r >> 1) & 3);   // XOR bank swizzle (r10)
            __builtin_amdgcn_global_load_lds(
                (const glb_u8*)(Ag + (size_t)r * DF + kt * 32 + qg * 8),
                base + (w * 64) * 16, 16, 0, 0);
        }
        // B: 512 chunks (128 rows x 4), two per thread
        const unsigned short* Bg = Mw + (size_t)n * DOUT * DF + (size_t)on0 * DF;
#pragma unroll
        for (int i = 0; i < 2; ++i) {
            const int cbase = i * 256 + w * 64;
            const int c = cbase + lane;
            const int r = c >> 2, qs = c & 3;
            const int qg = qs ^ ((r >> 1) & 3);
            __builtin_amdgcn_global_load_lds(
                (const glb_u8*)(Bg + (size_t)r * DF + kt * 32 + qg * 8),
                base + 4096 + cbase * 16, 16, 0, 0);
        }
    };

    f32x4 acc[2][4], Bacc[2][4];
#pragma unroll
    for (int i = 0; i < 2; i++)
#pragma unroll
        for (int j = 0; j < 4; j++) {
            acc[i][j]  = (f32x4){0.f, 0.f, 0.f, 0.f};
            Bacc[i][j] = (f32x4){0.f, 0.f, 0.f, 0.f};
        }

    stage(0);
    __syncthreads();

    const int lr  = lane & 15;
    const int q   = lane >> 4;
    const int qsw = (q ^ ((lr >> 1) & 3)) * 8;

    for (int m = 0; m < NF * 16; ++m) {
        if (m + 1 < NF * 16) stage(m + 1);

        const unsigned short* sAc = sAB + (m & 1) * 6144;
        const unsigned short* sBc = sAc + 2048;
        short8 a[2], b[4];
#pragma unroll
        for (int i = 0; i < 2; i++)
            a[i] = *(const short8*)&sAc[(wm * 32 + i * 16 + lr) * 32 + qsw];
#pragma unroll
        for (int j = 0; j < 4; j++)
            b[j] = *(const short8*)&sBc[(wn * 64 + j * 16 + lr) * 32 + qsw];
#pragma unroll
        for (int i = 0; i < 2; i++)
#pragma unroll
            for (int j = 0; j < 4; j++)
                acc[i][j] = __builtin_amdgcn_mfma_f32_16x16x32_bf16(
                    a[i], b[j], acc[i][j], 0, 0, 0);

        if ((m & 15) == 15) {
            // epilogue for n = m>>4: registers only (no LDS conflict w/ DMA)
            const int n = m >> 4;
#pragma unroll
            for (int i = 0; i < 2; i++) {
                const int rbase = wm * 32 + i * 16 + q * 4;
                float ph0 = sPhi2[n * 64 + rbase + 0];
                float ph1 = sPhi2[n * 64 + rbase + 1];
                float ph2 = sPhi2[n * 64 + rbase + 2];
                float ph3 = sPhi2[n * 64 + rbase + 3];
#pragma unroll
                for (int j = 0; j < 4; j++) {
                    float z0 = acc[i][j][0] * ph0;
                    float z1 = acc[i][j][1] * ph1;
                    float z2 = acc[i][j][2] * ph2;
                    float z3 = acc[i][j][3] * ph3;
                    float p0 = z0, p1 = p0 + z1, p2 = p1 + z2, p3 = p2 + z3;
                    float t  = __shfl_xor(p3, 16);   // partner q-group total
                    float off = (q & 1) ? t : 0.f;
                    Bacc[i][j][0] += ph0 * (off + p0);
                    Bacc[i][j][1] += ph1 * (off + p1);
                    Bacc[i][j][2] += ph2 * (off + p2);
                    Bacc[i][j][3] += ph3 * (off + p3);
                    if (q & 1) {   // rows 4-7 / 12-15 hold the chunk totals
                        int ch  = (rowL >> 3) + wm * 4 + i * 2 + (q >> 1);
                        int col = on0 + wn * 64 + j * 16 + lr;
                        Cs[((size_t)ch * NF + n) * 512 + col] = off + p3;
                    }
                    acc[i][j] = (f32x4){0.f, 0.f, 0.f, 0.f};
                }
            }
        }
        __syncthreads();
    }

    // B-term -> Out (fp32 set; k_apply adds the A-term)
#pragma unroll
    for (int i = 0; i < 2; i++)
#pragma unroll
        for (int j = 0; j < 4; j++)
#pragma unroll
            for (int r = 0; r < 4; r++) {
                int row = rowG + wm * 32 + i * 16 + q * 4 + r;
                Out[(size_t)row * DOUT + on0 + wn * 64 + j * 16 + lr] =
                    Bacc[i][j][r];
            }
}

// ---------------------------------------------------------------------------
// A-term: Out[t,o] += sum_n phi[t,n] * Gpref[chunk][n,o]. One block per
// chunk (8 rows x 512 cols, 2 cols/thread). Cs is L3-hot post-prefix.
// grid (nch_total), block 256.
// ---------------------------------------------------------------------------
__global__ __launch_bounds__(256, 8) void k_apply(
    float* __restrict__ Out, const float* __restrict__ Cs,
    const float* __restrict__ Fw, int r0)
{
    __shared__ float sP2[CHF * NF];
    const int c = blockIdx.x, tid = threadIdx.x;
    const int t0g = r0 + c * CHF;
    if (tid < CHF * NF)
        sP2[tid] = Fw[((t0g + tid / NF) & (TT - 1)) * NF + (tid % NF)];
    __syncthreads();

    const int col2 = tid * 2;
    float2 a[CHF];
#pragma unroll
    for (int t = 0; t < CHF; ++t) a[t] = make_float2(0.f, 0.f);
    const float* cb = Cs + (size_t)c * NF * 512 + col2;
#pragma unroll 6
    for (int n = 0; n < NF; ++n) {
        float2 g = *(const float2*)(cb + (size_t)n * 512);
#pragma unroll
        for (int t = 0; t < CHF; ++t) {
            float ph = sP2[t * NF + n];
            a[t].x += ph * g.x; a[t].y += ph * g.y;
        }
    }
#pragma unroll
    for (int t = 0; t < CHF; ++t) {
        float2* po = (float2*)&Out[(size_t)(t0g + t) * DOUT + col2];
        float2 o = *po;
        *po = make_float2(o.x + a[t].x, o.y + a[t].y);
    }
}

// ---------------------------------------------------------------------------
// SLOW GEMM (fallback for tiny ws): register staging + in-flight convert.
// ---------------------------------------------------------------------------
__global__ __launch_bounds__(256, 2) void k_gemm(
    const void* __restrict__ Xv, const void* __restrict__ Mv,
    const void* __restrict__ Fv, const int* __restrict__ flag,
    unsigned short* __restrict__ Z, int r0, int o0, int W)
{
    __shared__ unsigned short sA[128 * 32];
    __shared__ unsigned short sB[128 * 32];
    __shared__ unsigned short sC[128 * 136];
    __shared__ float sPhi[128];

    const int isf32 = *flag;
    const int tid  = threadIdx.x;
    const int lane = tid & 63;
    const int w    = tid >> 6;
    const int wm   = w & 1, wn = w >> 1;
    const int tm   = blockIdx.x;
    const int on0  = o0 + blockIdx.y * 128;
    const int n    = blockIdx.z;

    const int rowg0 = r0 + tm * 128;
    if (tid < 128) {
        int t = (rowg0 + tid) & (TT - 1);
        sPhi[tid] = isf32 ? ((const float*)Fv)[t * NF + n]
                          : bf2f(((const unsigned short*)Fv)[t * NF + n]);
    }

    const unsigned short* Ah = (const unsigned short*)Xv + (size_t)rowg0 * DF;
    const unsigned short* Bh = (const unsigned short*)Mv +
        (size_t)n * DOUT * DF + (size_t)on0 * DF;
    const float* Af = (const float*)Xv + (size_t)rowg0 * DF;
    const float* Bf = (const float*)Mv + (size_t)n * DOUT * DF + (size_t)on0 * DF;

    f32x4 acc[4][4];
#pragma unroll
    for (int i = 0; i < 4; i++)
#pragma unroll
        for (int j = 0; j < 4; j++) acc[i][j] = (f32x4){0.f, 0.f, 0.f, 0.f};

    for (int kt = 0; kt < DF / 32; ++kt) {
        __syncthreads();
        if (!isf32) {
            const unsigned short* Ak = Ah + kt * 32;
            const unsigned short* Bk = Bh + kt * 32;
#pragma unroll
            for (int i = 0; i < 2; ++i) {
                const int c = i * 256 + tid;
                const int r = c >> 2, cc = (c & 3) * 8;
                *(short8*)&sA[r * 32 + cc] = *(const short8*)(Ak + (size_t)r * DF + cc);
                *(short8*)&sB[r * 32 + cc] = *(const short8*)(Bk + (size_t)r * DF + cc);
            }
        } else {
            const float* Ak = Af + kt * 32;
            const float* Bk = Bf + kt * 32;
#pragma unroll
            for (int i = 0; i < 2; ++i) {
                const int c = i * 256 + tid;
                const int r = c >> 2, cc = (c & 3) * 8;
                float4 a0 = *(const float4*)(Ak + (size_t)r * DF + cc);
                float4 a1 = *(const float4*)(Ak + (size_t)r * DF + cc + 4);
                float4 b0 = *(const float4*)(Bk + (size_t)r * DF + cc);
                float4 b1 = *(const float4*)(Bk + (size_t)r * DF + cc + 4);
                short8 sa, sb;
                sa[0]=(short)f2bf(a0.x); sa[1]=(short)f2bf(a0.y);
                sa[2]=(short)f2bf(a0.z); sa[3]=(short)f2bf(a0.w);
                sa[4]=(short)f2bf(a1.x); sa[5]=(short)f2bf(a1.y);
                sa[6]=(short)f2bf(a1.z); sa[7]=(short)f2bf(a1.w);
                sb[0]=(short)f2bf(b0.x); sb[1]=(short)f2bf(b0.y);
                sb[2]=(short)f2bf(b0.z); sb[3]=(short)f2bf(b0.w);
                sb[4]=(short)f2bf(b1.x); sb[5]=(short)f2bf(b1.y);
                sb[6]=(short)f2bf(b1.z); sb[7]=(short)f2bf(b1.w);
                *(short8*)&sA[r * 32 + cc] = sa;
                *(short8*)&sB[r * 32 + cc] = sb;
            }
        }
        __syncthreads();

        const int lr = lane & 15;
        const int lk = (lane >> 4) * 8;
        short8 a[4], b[4];
#pragma unroll
        for (int i = 0; i < 4; i++)
            a[i] = *(const short8*)&sA[(wm * 64 + i * 16 + lr) * 32 + lk];
#pragma unroll
        for (int j = 0; j < 4; j++)
            b[j] = *(const short8*)&sB[(wn * 64 + j * 16 + lr) * 32 + lk];
#pragma unroll
        for (int i = 0; i < 4; i++)
#pragma unroll
            for (int j = 0; j < 4; j++)
                acc[i][j] = __builtin_amdgcn_mfma_f32_16x16x32_bf16(
                    a[i], b[j], acc[i][j], 0, 0, 0);
    }

    const int rb = (lane >> 4) * 4;
#pragma unroll
    for (int i = 0; i < 4; i++)
#pragma unroll
        for (int j = 0; j < 4; j++)
#pragma unroll
            for (int r = 0; r < 4; r++) {
                int row = wm * 64 + i * 16 + rb + r;
                sC[row * 136 + wn * 64 + j * 16 + (lane & 15)] =
                    f2bf(acc[i][j][r] * sPhi[row]);
            }
    __syncthreads();
#pragma unroll
    for (int it = 0; it < 8; ++it) {
        int row = it * 16 + (tid >> 4);
        int col = (tid & 15) * 8;
        uint4 v = *(const uint4*)&sC[row * 136 + col];
        *(uint4*)&Z[((size_t)(tm * 128 + row) * NF + n) * W + (on0 - o0) + col] = v;
    }
}

// ---------------------------------------------------------------------------
// Kernel 2a (slow tier only): chunk sums. grid (nch, NF), block W/2.
// ---------------------------------------------------------------------------
__global__ __launch_bounds__(256, 2) void k_csum(
    const unsigned short* __restrict__ Z, float* __restrict__ Cs,
    int W, int CHs)
{
    const int c = blockIdx.x, n = blockIdx.y, tid = threadIdx.x;
    const unsigned short* p = Z + ((size_t)(c * CHs) * NF + n) * W + tid * 2;
    float sx = 0.f, sy = 0.f;
#pragma unroll 8
    for (int t = 0; t < CHs; ++t) {
        unsigned int u = *(const unsigned int*)(p + (size_t)t * NF * W);
        sx += lo16f(u);
        sy += hi16f(u);
    }
    float2* q = (float2*)&Cs[((size_t)c * NF + n) * W + tid * 2];
    *q = make_float2(sx, sy);
}

// ---------------------------------------------------------------------------
// Kernel 2b: exclusive prefix over chunks (per batch; cross-pass carry Gc
// only when nbat==1). r17 cooperative form: 4 waves quarter the chunk range.
// grid = nbat*NF*(W/128) blocks of 256.
// ---------------------------------------------------------------------------
__global__ __launch_bounds__(256, 4) void k_prefix(
    float* __restrict__ Cs, float* __restrict__ Gc,
    int W, int rr, int nch, int nbat)
{
    __shared__ float2 sPart[4][64];
    const int tid  = threadIdx.x;
    const int wv   = tid >> 6, lane = tid & 63;
    const int obw  = W >> 7;
    const int perB = NF * obw;
    const int gw   = blockIdx.x;
    const int b    = gw / perB;
    const int rest = gw % perB;
    const int n    = rest / obw;
    const int ob   = rest % obw;
    const int opair = ob * 64 + lane;

    float* base = Cs + (size_t)b * nch * NF * W + (size_t)n * W + opair * 2;
    const size_t cstride = (size_t)NF * W;
    const int Q  = nch >> 2;
    const int c0 = wv * Q;
    const int end = c0 + Q;

    float sx = 0.f, sy = 0.f;
    for (int c = c0; c < end; ++c) {
        float2 v = *(const float2*)(base + (size_t)c * cstride);
        sx += v.x; sy += v.y;
    }
    sPart[wv][lane] = make_float2(sx, sy);
    __syncthreads();

    float cx = 0.f, cy = 0.f;
    if (nbat == 1 && rr != 0 && Gc) {
        float2 gv = *(const float2*)&Gc[(size_t)n * DOUT + opair * 2];
        cx = gv.x; cy = gv.y;
    }
    for (int w2 = 0; w2 < wv; ++w2) {
        float2 p = sPart[w2][lane];
        cx += p.x; cy += p.y;
    }

    int c = c0;
    if (Q >= 16) {
        float2 v[8], nx[8];
#pragma unroll
        for (int k = 0; k < 8; ++k)
            v[k] = *(float2*)(base + (size_t)(c + k) * cstride);
        for (; c + 16 <= end; c += 8) {
#pragma unroll
            for (int k = 0; k < 8; ++k)
                nx[k] = *(float2*)(base + (size_t)(c + 8 + k) * cstride);
#pragma unroll
            for (int k = 0; k < 8; ++k) {
                float2* p = (float2*)(base + (size_t)(c + k) * cstride);
                float2 t = v[k];
                *p = make_float2(cx, cy);
                cx += t.x; cy += t.y;
                v[k] = nx[k];
            }
        }
#pragma unroll
        for (int k = 0; k < 8; ++k) {
            float2* p = (float2*)(base + (size_t)(c + k) * cstride);
            float2 t = v[k];
            *p = make_float2(cx, cy);
            cx += t.x; cy += t.y;
        }
        c += 8;
    }
    for (; c < end; ++c) {
        float2* p = (float2*)(base + (size_t)c * cstride);
        float2 t = *p;
        *p = make_float2(cx, cy);
        cx += t.x; cy += t.y;
    }

    if (nbat == 1 && wv == 3 && Gc)
        *(float2*)&Gc[(size_t)n * DOUT + opair * 2] = make_float2(cx, cy);
}

// ---------------------------------------------------------------------------
// Kernel 2c GENERIC (slow tier only: any W, CHs=32). r17 form.
// grid (nch_total, W/128), block 256.
// ---------------------------------------------------------------------------
#define JLIST(F) F(0) F(1) F(2) F(3) F(4) F(5)

__global__ __launch_bounds__(256, 8) void k_scan(
    const unsigned short* __restrict__ Z, const float* __restrict__ Cs,
    const float* __restrict__ Fw, float* __restrict__ Out,
    int r0, int o0, int W, int CHs)
{
    __shared__ float sPhi[32 * NF];
    __shared__ float2 sP[4][8][64];
    const int cg = blockIdx.x, tid = threadIdx.x;
    const int g = tid >> 6, op = tid & 63;
    const int ng0 = g * 6;
    const int c2  = (blockIdx.y * 64 + op) * 2;
    const int act = (c2 + 2 <= W);
    const int c2u = act ? c2 : (W - 2);
    const int t0g = r0 + cg * CHs;
    const int t0 = t0g & (TT - 1);
    for (int i = tid; i < CHs * NF; i += 256)
        sPhi[i] = Fw[(t0 + i / NF) * NF + (i % NF)];
    __syncthreads();

#define DECLG(j) float gx##j, gy##j;
    JLIST(DECLG)
#define INITG2(j) { float2 v = *(const float2*)&Cs[((size_t)cg * NF + ng0 + j) * W + c2u]; \
                    gx##j = v.x; gy##j = v.y; }
    JLIST(INITG2)

    const unsigned short* zp = Z + ((size_t)cg * CHs * NF + ng0) * W + c2u;
    float* outb = Out + (size_t)t0g * DOUT + o0 + c2;
    for (int tb = 0; tb < CHs; tb += 8) {
#pragma unroll
        for (int tt = 0; tt < 8; ++tt) {
            float ax = 0.f, ay = 0.f;
            const float* php = &sPhi[(tb + tt) * NF + ng0];
#define UPDG2(j) { unsigned int u = *(const unsigned int*)(zp + (size_t)j * W); \
                   gx##j += lo16f(u); gy##j += hi16f(u); \
                   float ph = php[j]; ax += ph * gx##j; ay += ph * gy##j; }
            JLIST(UPDG2)
            sP[g][tt][op] = make_float2(ax, ay);
            zp += (size_t)NF * W;
        }
        __syncthreads();
#pragma unroll
        for (int k = 0; k < 2; ++k) {
            const int tt = g * 2 + k;
            float2 p0 = sP[0][tt][op], p1 = sP[1][tt][op],
                   p2 = sP[2][tt][op], p3 = sP[3][tt][op];
            if (act)
                *(float2*)(outb + (size_t)(tb + tt) * DOUT) =
                    make_float2(p0.x + p1.x + p2.x + p3.x,
                                p0.y + p1.y + p2.y + p3.y);
        }
        __syncthreads();
    }
}

// ---------------------------------------------------------------------------
extern "C" void kernel_launch(void* const* d_in, const int* in_sizes, int n_in,
                              void* d_out, int out_size, void* d_ws, size_t ws_size,
                              hipStream_t stream)
{
    const void* X = d_in[0]; const void* Fil = d_in[1]; const void* Mw = d_in[2];
    for (int i = 0; i < n_in && i < 3; ++i) {
        if (in_sizes[i] == BQ * TT * DF)        X   = d_in[i];
        else if (in_sizes[i] == TT * NF)        Fil = d_in[i];
        else if (in_sizes[i] == NF * DOUT * DF) Mw  = d_in[i];
    }
    float* Out = (float*)d_out;

    const size_t offF = 256;
    const size_t nbF  = (size_t)TT * NF * 4;
    const size_t off0 = offF + nbF;
    const size_t nbX  = (size_t)BQ * TT * DF * 2;    // 8.39 MB
    const size_t nbM  = (size_t)NF * DOUT * DF * 2;  // 12.58 MB
    const size_t nbGc = (size_t)NF * DOUT * 4;

    int* flag = (int*)d_ws;
    float* Fw = (float*)((char*)d_ws + offF);

    const int n4x = BQ * TT * DF / 4;
    const int n4m = NF * DOUT * DF / 4;
    const int n4f = TT * NF / 4;

    // ---- r20 single-pass no-Z tier: ws = X + M + Cs(full 50.3MB) ----
    {
        const size_t csB = (size_t)(BQ * TT / CHF) * NF * 512 * 4;   // 50.3 MB
        if (off0 + nbX + nbM + csB <= ws_size) {
            unsigned short* Xbf = (unsigned short*)((char*)d_ws + off0);
            unsigned short* Mbf = (unsigned short*)((char*)Xbf + nbX);
            float* Cs = (float*)((char*)Mbf + nbM);

            hipLaunchKernelGGL(k_prep, dim3(2048), dim3(256), 0, stream,
                               X, Mw, Fil, Xbf, Mbf, Fw, n4x, n4m, n4f);
            hipLaunchKernelGGL(k_gemm_ns, dim3(BQ * TT / 64, 4), dim3(256),
                               0, stream, Xbf, Mbf, Fw, Cs, Out, 0);
            hipLaunchKernelGGL(k_prefix, dim3(BQ * NF * 4), dim3(256),
                               0, stream, Cs, (float*)nullptr, 512, 0,
                               TT / CHF, BQ);
            hipLaunchKernelGGL(k_apply, dim3(BQ * TT / CHF), dim3(256),
                               0, stream, Out, Cs, Fw, 0);
            return;
        }
    }

    // ---- Per-batch no-Z tier: ws = X + M + Cs(12.6MB) ----
    {
        const size_t csB = (size_t)(TT / CHF) * NF * 512 * 4;        // 12.6 MB
        if (off0 + nbX + nbM + csB <= ws_size) {
            unsigned short* Xbf = (unsigned short*)((char*)d_ws + off0);
            unsigned short* Mbf = (unsigned short*)((char*)Xbf + nbX);
            float* Cs = (float*)((char*)Mbf + nbM);

            hipLaunchKernelGGL(k_prep, dim3(2048), dim3(256), 0, stream,
                               X, Mw, Fil, Xbf, Mbf, Fw, n4x, n4m, n4f);
            for (int b = 0; b < BQ; ++b) {
                const int r0 = b * TT;
                hipLaunchKernelGGL(k_gemm_ns, dim3(TT / 64, 4), dim3(256),
                                   0, stream, Xbf, Mbf, Fw, Cs, Out, r0);
                hipLaunchKernelGGL(k_prefix, dim3(NF * 4), dim3(256),
                                   0, stream, Cs, (float*)nullptr, 512, 0,
                                   TT / CHF, 1);
                hipLaunchKernelGGL(k_apply, dim3(TT / CHF), dim3(256),
                                   0, stream, Out, Cs, Fw, r0);
            }
            return;
        }
    }

    // ---- Slow tiers (tiny ws): in-kernel convert GEMM, o-sliced, CH=32 ----
    hipLaunchKernelGGL(k_detect, dim3(1), dim3(64), 0, stream,
                       (const unsigned int*)X, flag);
    hipLaunchKernelGGL(k_convf, dim3(192), dim3(256), 0, stream,
                       Fil, Fw, flag, TT * NF);

    static const int cRT[7] = {2048, 1024, 512, 256, 128, 128, 128};
    static const int cW[7]  = {512, 512, 512, 512, 512, 256, 128};
    int RTs = 128, W = 128;
    for (int ci = 0; ci < 7; ++ci) {
        size_t need = off0 + (size_t)cRT[ci] * NF * cW[ci] * 2
                    + (size_t)(cRT[ci] / 32) * NF * cW[ci] * 4 + nbGc;
        if (need <= ws_size) { RTs = cRT[ci]; W = cW[ci]; break; }
    }
    unsigned short* Z = (unsigned short*)((char*)d_ws + off0);
    float* Cs = (float*)((char*)Z + (size_t)RTs * NF * W * 2);
    float* Gc = (float*)((char*)Cs + (size_t)(RTs / 32) * NF * W * 4);

    const int nrr = TT / RTs, nch = RTs / 32;
    for (int b = 0; b < BQ; ++b) {
        for (int o0 = 0; o0 < DOUT; o0 += W) {
            for (int rr = 0; rr < nrr; ++rr) {
                const int r0 = b * TT + rr * RTs;
                hipLaunchKernelGGL(k_gemm, dim3(RTs / 128, W / 128, NF), dim3(256),
                                   0, stream, X, Mw, Fil, flag, Z, r0, o0, W);
                hipLaunchKernelGGL(k_csum, dim3(nch, NF), dim3(W / 2), 0, stream,
                                   Z, Cs, W, 32);
                hipLaunchKernelGGL(k_prefix, dim3(NF * (W / 128)), dim3(256),
                                   0, stream, Cs, Gc, W, rr, nch, 1);
                hipLaunchKernelGGL(k_scan, dim3(nch, W / 128), dim3(256),
                                   0, stream, Z, Cs, Fw, Out, r0, o0, W, 32);
            }
        }
    }
}